// Round 1
// baseline (32.237 us; speedup 1.0000x reference)
//
#include <hip/hip_runtime.h>

// Problem constants (match reference)
#define BB 8192
#define PP 2048
#define LL 1024
#define OO 1000

// ws layout (float offsets):
//   [0, 1024)        colsum
//   [1024, 2048)     wsum (1000 used)
//   [2048]           proto_sq
//   [2112, 2368)     sqpart (256 = 4 col-chunks x 64 row-chunks)
//   [4096, 4096+64*1024) pcolsum partials
#define WS_COLSUM 0
#define WS_WSUM   1024
#define WS_PSQ    2048
#define WS_SQPART 2112
#define WS_PCOL   4096

// ---- Kernel 1a: partial prototype column sums + sum of squares ----
// grid (4 col-chunks, 64 row-chunks), block 256
__global__ void __launch_bounds__(256) k1a_proto_partial(
        const float* __restrict__ proto, float* __restrict__ ws) {
    const int bx = blockIdx.x;   // column chunk 0..3
    const int by = blockIdx.y;   // row chunk 0..63 (32 rows each)
    const int t  = threadIdx.x;  // 0..255
    const int c  = bx * 256 + t; // column 0..1023
    float csum = 0.f, sq = 0.f;
    const int p0 = by * 32;
#pragma unroll 8
    for (int p = p0; p < p0 + 32; ++p) {
        float v = proto[(size_t)p * LL + c];
        csum += v;
        sq   += v * v;
    }
    ws[WS_PCOL + by * LL + c] = csum;
    __shared__ float red[256];
    red[t] = sq;
    __syncthreads();
    for (int s = 128; s > 0; s >>= 1) {
        if (t < s) red[t] += red[t + s];
        __syncthreads();
    }
    if (t == 0) ws[WS_SQPART + by * 4 + bx] = red[0];
}

// ---- Kernel 1b: finalize colsum + proto_sq ---- (1 block x 1024 threads)
__global__ void __launch_bounds__(1024) k1b_proto_final(float* __restrict__ ws) {
    const int t = threadIdx.x; // 0..1023
    float s = 0.f;
#pragma unroll 8
    for (int r = 0; r < 64; ++r) s += ws[WS_PCOL + r * LL + t];
    ws[WS_COLSUM + t] = s;
    __shared__ float red[256];
    if (t < 256) red[t] = ws[WS_SQPART + t];
    __syncthreads();
    for (int s2 = 128; s2 > 0; s2 >>= 1) {
        if (t < s2) red[t] += red[t + s2];
        __syncthreads();
    }
    if (t == 0) ws[WS_PSQ] = red[0];
}

// ---- Kernel 2: wsum[o] = sum_p weight[o,p] ---- (250 blocks x 256, 1 wave/row)
__global__ void __launch_bounds__(256) k2_wsum(
        const float* __restrict__ w, float* __restrict__ ws) {
    const int t = threadIdx.x;
    const int wave = t >> 6, lane = t & 63;
    const int o = blockIdx.x * 4 + wave;        // < 1000 always (250*4)
    const float4* row = (const float4*)(w + (size_t)o * PP);  // 512 float4
    float s = 0.f;
#pragma unroll
    for (int k = 0; k < 8; ++k) {
        float4 v = row[lane + 64 * k];
        s += v.x + v.y + v.z + v.w;
    }
    for (int off = 32; off > 0; off >>= 1) s += __shfl_down(s, off, 64);
    if (lane == 0) ws[WS_WSUM + o] = s;
}

// ---- Kernel 3: per-sample distance + output row ---- (8192 blocks x 256)
__global__ void __launch_bounds__(256) k3_main(
        const float* __restrict__ x, const float* __restrict__ bias,
        const float* __restrict__ ws, float* __restrict__ out) {
    const int b = blockIdx.x;
    const int t = threadIdx.x;
    const float4* xr = (const float4*)(x + (size_t)b * LL);   // 256 float4
    const float4* cs = (const float4*)(ws + WS_COLSUM);
    float4 xv = xr[t];
    float4 cv = cs[t];
    float sumsq = xv.x * xv.x + xv.y * xv.y + xv.z * xv.z + xv.w * xv.w;
    float dotc  = xv.x * cv.x + xv.y * cv.y + xv.z * cv.z + xv.w * cv.w;
    for (int off = 32; off > 0; off >>= 1) {
        sumsq += __shfl_down(sumsq, off, 64);
        dotc  += __shfl_down(dotc,  off, 64);
    }
    __shared__ float s_sq[4], s_dc[4], s_d;
    const int wave = t >> 6, lane = t & 63;
    if (lane == 0) { s_sq[wave] = sumsq; s_dc[wave] = dotc; }
    __syncthreads();
    if (t == 0) {
        float ss = s_sq[0] + s_sq[1] + s_sq[2] + s_sq[3];
        float dc = s_dc[0] + s_dc[1] + s_dc[2] + s_dc[3];
        float sq = (float)PP * ss - 2.f * dc + ws[WS_PSQ];
        s_d = sqrtf(sq);
    }
    __syncthreads();
    const float d = s_d;
    if (t < 250) {
        float4 wv = ((const float4*)(ws + WS_WSUM))[t];
        float4 bv = ((const float4*)bias)[t];
        float4 ov;
        ov.x = d * wv.x + bv.x;
        ov.y = d * wv.y + bv.y;
        ov.z = d * wv.z + bv.z;
        ov.w = d * wv.w + bv.w;
        ((float4*)(out + (size_t)b * OO))[t] = ov;
    }
}

extern "C" void kernel_launch(void* const* d_in, const int* in_sizes, int n_in,
                              void* d_out, int out_size, void* d_ws, size_t ws_size,
                              hipStream_t stream) {
    const float* input = (const float*)d_in[0];   // [B, L]
    const float* proto = (const float*)d_in[1];   // [P, L]
    const float* weight = (const float*)d_in[2];  // [O, P]
    const float* bias = (const float*)d_in[3];    // [O]
    float* out = (float*)d_out;                   // [B, O]
    float* ws = (float*)d_ws;

    k1a_proto_partial<<<dim3(4, 64), 256, 0, stream>>>(proto, ws);
    k1b_proto_final<<<1, 1024, 0, stream>>>(ws);
    k2_wsum<<<250, 256, 0, stream>>>(weight, ws);
    k3_main<<<BB, 256, 0, stream>>>(input, bias, ws, out);
}